// Round 1
// baseline (120.922 us; speedup 1.0000x reference)
//
#include <hip/hip_runtime.h>

#define N_NODES 10000
#define N_EDGES 640000
#define D 128
#define NSHARD 8
#define SLOTS 64                       // 64 ushorts = 128 B = ONE cache line per
                                       // (node,shard): no cross-XCD false sharing
#define NODE_STRIDE (NSHARD * SLOTS)   // 512 ushorts = 1 KB per node

typedef __attribute__((ext_vector_type(8))) short bf16x8;
typedef __attribute__((ext_vector_type(4))) float f32x4;

// ws layout (int units):
//   edge_src : 10000*512 ushort = 2,560,000 ints (10.24 MB)
//   cnt      : 10000 uint2 (8 byte-counters/node, packed) = 20,000 ints (80 KB)
//   y        : 1.28M bf16       =   640,000 ints (y = x @ W^T, bf16)
#define WS_EDGESRC 0
#define WS_CNT     2560000
#define WS_Y       2640000

#define GEMM_BLOCKS 157                // ceil(10000/64)
#define SCAT_BLOCKS (N_EDGES / 256)    // 2500

__device__ __forceinline__ unsigned bf16_rtne(unsigned u) {
    return (u + 0x7fffu + ((u >> 16) & 1u)) >> 16;
}
__device__ __forceinline__ float blo(unsigned v) { return __uint_as_float(v << 16); }
__device__ __forceinline__ float bhi(unsigned v) { return __uint_as_float(v & 0xffff0000u); }

// ---------------------------------------------------------------------------
// Mega-kernel: blocks [0,157) compute y = x @ W^T (bf16 MFMA); blocks
// [157, 2657) do the padded bucket scatter.
// Scatter uses BYTE-PACKED counters: cnt[node] = uint2 holding 8 one-byte
// shard counters. atomicAdd of 1<<(8*(sh&3)) on word (sh>>2) returns the old
// packed word; our slot is that byte. Counts are ~Poisson(8) per
// (node,shard) -> byte overflow (>=256) has probability ~0; slots >= SLOTS
// dropped exactly as before. 4x smaller atomic working set (80 KB).
// ---------------------------------------------------------------------------
#define WLD 136
__global__ __launch_bounds__(256) void fused_gemm_scatter_kernel(
    const float* __restrict__ x,
    const float* __restrict__ W,
    const int* __restrict__ src,
    const int* __restrict__ dst,
    unsigned* __restrict__ cnt,        // [N_NODES][2] packed bytes, pre-zeroed
    unsigned short* __restrict__ edge_src,
    unsigned short* __restrict__ y) {
    __shared__ __align__(16) unsigned short Wl[D * WLD];   // 34.8 KB

    int t = threadIdx.x;

    if (blockIdx.x >= GEMM_BLOCKS) {
        int bb = blockIdx.x - GEMM_BLOCKS;
        int i = bb * 256 + t;
        int s = src[i];
        int d = dst[i];
        int sh = bb & (NSHARD - 1);
        unsigned shift = (unsigned)((sh & 3) * 8);
        unsigned old = atomicAdd(&cnt[d * 2 + (sh >> 2)], 1u << shift);
        int p = (int)((old >> shift) & 0xffu);
        if (p < SLOTS)
            edge_src[d * NODE_STRIDE + sh * SLOTS + p] = (unsigned short)s;
        return;
    }

    {
        const uint2* W2 = (const uint2*)W;
        #pragma unroll
        for (int u = t; u < 8192; u += 256) {
            uint2 w = W2[u];
            unsigned p = bf16_rtne(w.x) | (bf16_rtne(w.y) << 16);
            int row = u >> 6;
            int c2  = u & 63;
            *(unsigned*)&Wl[row * WLD + c2 * 2] = p;
        }
    }
    __syncthreads();

    int wave = t >> 6;
    int lane = t & 63;
    int l16  = lane & 15;
    int quad = lane >> 4;

    int m0 = blockIdx.x * 64 + wave * 16;
    int anode = m0 + l16;
    if (anode >= N_NODES) anode = N_NODES - 1;

    f32x4 acc[8];
    #pragma unroll
    for (int i = 0; i < 8; ++i) acc[i] = (f32x4){0.f, 0.f, 0.f, 0.f};

    #pragma unroll
    for (int ks = 0; ks < 4; ++ks) {
        const uint4* ap = (const uint4*)(x + anode * D + ks * 32 + quad * 8);
        uint4 a0 = ap[0];
        uint4 a1 = ap[1];
        union { unsigned u[4]; bf16x8 v; } af;
        af.u[0] = bf16_rtne(a0.x) | (bf16_rtne(a0.y) << 16);
        af.u[1] = bf16_rtne(a0.z) | (bf16_rtne(a0.w) << 16);
        af.u[2] = bf16_rtne(a1.x) | (bf16_rtne(a1.y) << 16);
        af.u[3] = bf16_rtne(a1.z) | (bf16_rtne(a1.w) << 16);
        #pragma unroll
        for (int ot = 0; ot < 8; ++ot) {
            bf16x8 bf = *(const bf16x8*)&Wl[(ot * 16 + l16) * WLD + ks * 32 + quad * 8];
            acc[ot] = __builtin_amdgcn_mfma_f32_16x16x32_bf16(af.v, bf, acc[ot], 0, 0, 0);
        }
    }

    #pragma unroll
    for (int ot = 0; ot < 8; ++ot) {
        int o = ot * 16 + l16;
        #pragma unroll
        for (int r = 0; r < 4; ++r) {
            int node = m0 + quad * 4 + r;
            if (node < N_NODES)
                y[node * D + o] = (unsigned short)bf16_rtne(__float_as_uint(acc[ot][r]));
        }
    }
}

// ---------------------------------------------------------------------------
// Aggregation v3: one WAVE per node (4 waves/block, 2500 blocks). Quarter-
// wave `p` handles shard-pair {p, p+4}. Changes vs v2:
//   * cnt: ONE uint2 load gives both shard counts (byte-packed, 80 KB total).
//   * seg index lines software-pipelined: batch j+8's uint4s prefetched while
//     batch j is processed (kills the per-batch ~200-cycle dependent stall).
//   * cross-shard combine via 2x __shfl_xor (lane^16, lane^32) -- no LDS, no
//     __syncthreads; waves retire independently (less tail coupling).
// ---------------------------------------------------------------------------
__global__ __launch_bounds__(256) void agg_kernel(
    const uint4* __restrict__ y4,                // [N_NODES][16] uint4
    const unsigned short* __restrict__ edge_src, // [N_NODES][8][64]
    const uint2* __restrict__ cnt8,              // [N_NODES] packed byte cnts
    const float* __restrict__ b,
    float4* __restrict__ out4) {                 // [N_NODES][32] float4
    int t = threadIdx.x;
    int wave = t >> 6;
    int lane = t & 63;
    int p = lane >> 4;               // shard-pair 0..3 (quarter-wave)
    int l = lane & 15;               // col group (8 bf16 = 32 B fp32 out)
    int n = blockIdx.x * 4 + wave;   // 2500 blocks x 4 nodes = 10000 exactly

    uint2 cw = cnt8[n];
    int cA = (int)((cw.x >> (p * 8)) & 0xffu);
    int cB = (int)((cw.y >> (p * 8)) & 0xffu);
    if (cA > SLOTS) cA = SLOTS;
    if (cB > SLOTS) cB = SLOTS;
    const unsigned short* segA = edge_src + n * NODE_STRIDE + p * SLOTS;
    const unsigned short* segB = segA + 4 * SLOTS;
    int nb = cA > cB ? cA : cB;

    float acc[8];
    #pragma unroll
    for (int i = 0; i < 8; ++i) acc[i] = 0.f;

    // Unconditional preload of batch 0 (lines are inside the always-
    // allocated edge_src region even when cnt==0).
    uint4 sA = *(const uint4*)segA;
    uint4 sB = *(const uint4*)segB;

    for (int j = 0; j < nb; j += 8) {
        uint4 aV = sA;
        uint4 bV = sB;
        if (j + 8 < nb) {                        // prefetch next batch
            sA = *(const uint4*)(segA + j + 8);
            sB = *(const uint4*)(segB + j + 8);
        }
        unsigned iA[8], iB[8];
        iA[0] = aV.x & 0xffffu; iA[1] = aV.x >> 16;
        iA[2] = aV.y & 0xffffu; iA[3] = aV.y >> 16;
        iA[4] = aV.z & 0xffffu; iA[5] = aV.z >> 16;
        iA[6] = aV.w & 0xffffu; iA[7] = aV.w >> 16;
        iB[0] = bV.x & 0xffffu; iB[1] = bV.x >> 16;
        iB[2] = bV.y & 0xffffu; iB[3] = bV.y >> 16;
        iB[4] = bV.z & 0xffffu; iB[5] = bV.z >> 16;
        iB[6] = bV.w & 0xffffu; iB[7] = bV.w >> 16;
        #pragma unroll
        for (int u = 0; u < 8; ++u) {
            unsigned mA = (j + u < cA) ? 0xffffffffu : 0u;
            unsigned mB = (j + u < cB) ? 0xffffffffu : 0u;
            uint4 vA = y4[iA[u] * 16 + l];       // poison idx stays inside ws
            uint4 vB = y4[iB[u] * 16 + l];
            vA.x &= mA; vA.y &= mA; vA.z &= mA; vA.w &= mA;
            vB.x &= mB; vB.y &= mB; vB.z &= mB; vB.w &= mB;
            acc[0] += blo(vA.x) + blo(vB.x); acc[1] += bhi(vA.x) + bhi(vB.x);
            acc[2] += blo(vA.y) + blo(vB.y); acc[3] += bhi(vA.y) + bhi(vB.y);
            acc[4] += blo(vA.z) + blo(vB.z); acc[5] += bhi(vA.z) + bhi(vB.z);
            acc[6] += blo(vA.w) + blo(vB.w); acc[7] += bhi(vA.w) + bhi(vB.w);
        }
    }

    // Combine the 4 shard-pair partials living in this wave's 4 quarter-
    // waves: butterfly over lane^16 then lane^32.
    #pragma unroll
    for (int k = 0; k < 8; ++k) {
        acc[k] += __shfl_xor(acc[k], 16);
        acc[k] += __shfl_xor(acc[k], 32);
    }

    if (p == 0) {
        const float4* b4 = (const float4*)b;
        float4 b0 = b4[l * 2], b1 = b4[l * 2 + 1];
        out4[n * 32 + l * 2]     = make_float4(acc[0] + b0.x, acc[1] + b0.y,
                                               acc[2] + b0.z, acc[3] + b0.w);
        out4[n * 32 + l * 2 + 1] = make_float4(acc[4] + b1.x, acc[5] + b1.y,
                                               acc[6] + b1.z, acc[7] + b1.w);
    }
}

// ---------------------------------------------------------------------------
extern "C" void kernel_launch(void* const* d_in, const int* in_sizes, int n_in,
                              void* d_out, int out_size, void* d_ws, size_t ws_size,
                              hipStream_t stream) {
    const float* x   = (const float*)d_in[0];
    const int*   src = (const int*)  d_in[1];
    const int*   dst = (const int*)  d_in[2];
    const float* W   = (const float*)d_in[3];
    const float* b   = (const float*)d_in[4];
    float* out = (float*)d_out;

    int* wsI = (int*)d_ws;
    unsigned short* edge_src = (unsigned short*)(wsI + WS_EDGESRC);
    unsigned* cnt = (unsigned*)(wsI + WS_CNT);
    unsigned short* y = (unsigned short*)(wsI + WS_Y);

    // 1) zero packed scatter counters (80 KB, was 320 KB)
    hipMemsetAsync(cnt, 0, N_NODES * 2 * sizeof(unsigned), stream);

    // 2) fused: y = x @ W^T (blocks 0..156) + bucket scatter (blocks 157..2656)
    fused_gemm_scatter_kernel<<<GEMM_BLOCKS + SCAT_BLOCKS, 256, 0, stream>>>(
        x, W, src, dst, cnt, edge_src, y);

    // 3) aggregate v3: wave per node, shfl-combine, pipelined seg loads
    agg_kernel<<<N_NODES / 4, 256, 0, stream>>>(
        (const uint4*)y, edge_src, (const uint2*)cnt, b, (float4*)out);
}

// Round 2
// 114.330 us; speedup vs baseline: 1.0577x; 1.0577x over previous
//
#include <hip/hip_runtime.h>

#define N_NODES 10000
#define N_EDGES 640000
#define D 128
#define NSHARD 8
#define SLOTS 64                       // 64 ushorts = 128 B = ONE cache line per
                                       // (node,shard): no cross-XCD false sharing
#define NODE_STRIDE (NSHARD * SLOTS)   // 512 ushorts = 1 KB per node

typedef __attribute__((ext_vector_type(8))) short bf16x8;
typedef __attribute__((ext_vector_type(4))) float f32x4;

// ws layout (int units):
//   edge_src : 10000*512 ushort = 2,560,000 ints (10.24 MB)
//   cnt      : 8 x 10000        =    80,000 ints (per-shard arrays: atomics
//              spread over 8 words / 8 lines per node -- R1's byte-packing
//              serialized them 4x and regressed; reverted)
//   y        : 1.28M bf16       =   640,000 ints (y = x @ W^T, bf16)
#define WS_EDGESRC 0
#define WS_CNT     2560000
#define WS_Y       2640000

#define GEMM_BLOCKS 157                // ceil(10000/64)
#define SCAT_BLOCKS (N_EDGES / 256)    // 2500

__device__ __forceinline__ unsigned bf16_rtne(unsigned u) {
    return (u + 0x7fffu + ((u >> 16) & 1u)) >> 16;
}
__device__ __forceinline__ float blo(unsigned v) { return __uint_as_float(v << 16); }
__device__ __forceinline__ float bhi(unsigned v) { return __uint_as_float(v & 0xffff0000u); }

// ---------------------------------------------------------------------------
// Mega-kernel (scatter reverted to R0 form): blocks [0,157) compute
// y = x @ W^T (bf16 MFMA); blocks [157, 2657) do the padded bucket scatter
// with one atomicAdd per edge on the per-shard counter array.
// ---------------------------------------------------------------------------
#define WLD 136
__global__ __launch_bounds__(256) void fused_gemm_scatter_kernel(
    const float* __restrict__ x,
    const float* __restrict__ W,
    const int* __restrict__ src,
    const int* __restrict__ dst,
    int* __restrict__ cnt,             // [8][N_NODES], pre-zeroed
    unsigned short* __restrict__ edge_src,
    unsigned short* __restrict__ y) {
    __shared__ __align__(16) unsigned short Wl[D * WLD];   // 34.8 KB

    int t = threadIdx.x;

    if (blockIdx.x >= GEMM_BLOCKS) {
        int bb = blockIdx.x - GEMM_BLOCKS;
        int i = bb * 256 + t;
        int s = src[i];
        int d = dst[i];
        int sh = bb & (NSHARD - 1);
        int p = atomicAdd(&cnt[sh * N_NODES + d], 1);
        if (p < SLOTS)
            edge_src[d * NODE_STRIDE + sh * SLOTS + p] = (unsigned short)s;
        return;
    }

    {
        const uint2* W2 = (const uint2*)W;
        #pragma unroll
        for (int u = t; u < 8192; u += 256) {
            uint2 w = W2[u];
            unsigned p = bf16_rtne(w.x) | (bf16_rtne(w.y) << 16);
            int row = u >> 6;
            int c2  = u & 63;
            *(unsigned*)&Wl[row * WLD + c2 * 2] = p;
        }
    }
    __syncthreads();

    int wave = t >> 6;
    int lane = t & 63;
    int l16  = lane & 15;
    int quad = lane >> 4;

    int m0 = blockIdx.x * 64 + wave * 16;
    int anode = m0 + l16;
    if (anode >= N_NODES) anode = N_NODES - 1;

    f32x4 acc[8];
    #pragma unroll
    for (int i = 0; i < 8; ++i) acc[i] = (f32x4){0.f, 0.f, 0.f, 0.f};

    #pragma unroll
    for (int ks = 0; ks < 4; ++ks) {
        const uint4* ap = (const uint4*)(x + anode * D + ks * 32 + quad * 8);
        uint4 a0 = ap[0];
        uint4 a1 = ap[1];
        union { unsigned u[4]; bf16x8 v; } af;
        af.u[0] = bf16_rtne(a0.x) | (bf16_rtne(a0.y) << 16);
        af.u[1] = bf16_rtne(a0.z) | (bf16_rtne(a0.w) << 16);
        af.u[2] = bf16_rtne(a1.x) | (bf16_rtne(a1.y) << 16);
        af.u[3] = bf16_rtne(a1.z) | (bf16_rtne(a1.w) << 16);
        #pragma unroll
        for (int ot = 0; ot < 8; ++ot) {
            bf16x8 bf = *(const bf16x8*)&Wl[(ot * 16 + l16) * WLD + ks * 32 + quad * 8];
            acc[ot] = __builtin_amdgcn_mfma_f32_16x16x32_bf16(af.v, bf, acc[ot], 0, 0, 0);
        }
    }

    #pragma unroll
    for (int ot = 0; ot < 8; ++ot) {
        int o = ot * 16 + l16;
        #pragma unroll
        for (int r = 0; r < 4; ++r) {
            int node = m0 + quad * 4 + r;
            if (node < N_NODES)
                y[node * D + o] = (unsigned short)bf16_rtne(__float_as_uint(acc[ot][r]));
        }
    }
}

// ---------------------------------------------------------------------------
// Aggregation v3b: one WAVE per node (4 waves/block, 2500 blocks). Quarter-
// wave `p` handles shard-pair {p, p+4}. Kept from v3:
//   * seg index lines software-pipelined: batch j+8's uint4s prefetched while
//     batch j is processed (kills the per-batch ~200-cycle dependent stall).
//   * cross-shard combine via 2x __shfl_xor (lane^16, lane^32) -- no LDS, no
//     __syncthreads; waves retire independently.
// Reverted from v3: cnt is back to two scalar loads from the per-shard
// arrays (the byte-packed counter was the scatter-side regression).
// ---------------------------------------------------------------------------
__global__ __launch_bounds__(256) void agg_kernel(
    const uint4* __restrict__ y4,                // [N_NODES][16] uint4
    const unsigned short* __restrict__ edge_src, // [N_NODES][8][64]
    const int* __restrict__ cnt,                 // [8][N_NODES]
    const float* __restrict__ b,
    float4* __restrict__ out4) {                 // [N_NODES][32] float4
    int t = threadIdx.x;
    int wave = t >> 6;
    int lane = t & 63;
    int p = lane >> 4;               // shard-pair 0..3 (quarter-wave)
    int l = lane & 15;               // col group (8 bf16 = 32 B fp32 out)
    int n = blockIdx.x * 4 + wave;   // 2500 blocks x 4 nodes = 10000 exactly

    int cA = cnt[p * N_NODES + n];
    int cB = cnt[(p + 4) * N_NODES + n];
    if (cA > SLOTS) cA = SLOTS;
    if (cB > SLOTS) cB = SLOTS;
    const unsigned short* segA = edge_src + n * NODE_STRIDE + p * SLOTS;
    const unsigned short* segB = segA + 4 * SLOTS;
    int nb = cA > cB ? cA : cB;

    float acc[8];
    #pragma unroll
    for (int i = 0; i < 8; ++i) acc[i] = 0.f;

    // Unconditional preload of batch 0 (lines are inside the always-
    // allocated edge_src region even when cnt==0).
    uint4 sA = *(const uint4*)segA;
    uint4 sB = *(const uint4*)segB;

    for (int j = 0; j < nb; j += 8) {
        uint4 aV = sA;
        uint4 bV = sB;
        if (j + 8 < nb) {                        // prefetch next batch
            sA = *(const uint4*)(segA + j + 8);
            sB = *(const uint4*)(segB + j + 8);
        }
        unsigned iA[8], iB[8];
        iA[0] = aV.x & 0xffffu; iA[1] = aV.x >> 16;
        iA[2] = aV.y & 0xffffu; iA[3] = aV.y >> 16;
        iA[4] = aV.z & 0xffffu; iA[5] = aV.z >> 16;
        iA[6] = aV.w & 0xffffu; iA[7] = aV.w >> 16;
        iB[0] = bV.x & 0xffffu; iB[1] = bV.x >> 16;
        iB[2] = bV.y & 0xffffu; iB[3] = bV.y >> 16;
        iB[4] = bV.z & 0xffffu; iB[5] = bV.z >> 16;
        iB[6] = bV.w & 0xffffu; iB[7] = bV.w >> 16;
        #pragma unroll
        for (int u = 0; u < 8; ++u) {
            unsigned mA = (j + u < cA) ? 0xffffffffu : 0u;
            unsigned mB = (j + u < cB) ? 0xffffffffu : 0u;
            uint4 vA = y4[iA[u] * 16 + l];       // poison idx stays inside ws
            uint4 vB = y4[iB[u] * 16 + l];
            vA.x &= mA; vA.y &= mA; vA.z &= mA; vA.w &= mA;
            vB.x &= mB; vB.y &= mB; vB.z &= mB; vB.w &= mB;
            acc[0] += blo(vA.x) + blo(vB.x); acc[1] += bhi(vA.x) + bhi(vB.x);
            acc[2] += blo(vA.y) + blo(vB.y); acc[3] += bhi(vA.y) + bhi(vB.y);
            acc[4] += blo(vA.z) + blo(vB.z); acc[5] += bhi(vA.z) + bhi(vB.z);
            acc[6] += blo(vA.w) + blo(vB.w); acc[7] += bhi(vA.w) + bhi(vB.w);
        }
    }

    // Combine the 4 shard-pair partials living in this wave's 4 quarter-
    // waves: butterfly over lane^16 then lane^32.
    #pragma unroll
    for (int k = 0; k < 8; ++k) {
        acc[k] += __shfl_xor(acc[k], 16);
        acc[k] += __shfl_xor(acc[k], 32);
    }

    if (p == 0) {
        const float4* b4 = (const float4*)b;
        float4 b0 = b4[l * 2], b1 = b4[l * 2 + 1];
        out4[n * 32 + l * 2]     = make_float4(acc[0] + b0.x, acc[1] + b0.y,
                                               acc[2] + b0.z, acc[3] + b0.w);
        out4[n * 32 + l * 2 + 1] = make_float4(acc[4] + b1.x, acc[5] + b1.y,
                                               acc[6] + b1.z, acc[7] + b1.w);
    }
}

// ---------------------------------------------------------------------------
extern "C" void kernel_launch(void* const* d_in, const int* in_sizes, int n_in,
                              void* d_out, int out_size, void* d_ws, size_t ws_size,
                              hipStream_t stream) {
    const float* x   = (const float*)d_in[0];
    const int*   src = (const int*)  d_in[1];
    const int*   dst = (const int*)  d_in[2];
    const float* W   = (const float*)d_in[3];
    const float* b   = (const float*)d_in[4];
    float* out = (float*)d_out;

    int* wsI = (int*)d_ws;
    unsigned short* edge_src = (unsigned short*)(wsI + WS_EDGESRC);
    int* cnt = wsI + WS_CNT;
    unsigned short* y = (unsigned short*)(wsI + WS_Y);

    // 1) zero scatter counters (320 KB, per-shard arrays)
    hipMemsetAsync(cnt, 0, NSHARD * N_NODES * sizeof(int), stream);

    // 2) fused: y = x @ W^T (blocks 0..156) + bucket scatter (blocks 157..2656)
    fused_gemm_scatter_kernel<<<GEMM_BLOCKS + SCAT_BLOCKS, 256, 0, stream>>>(
        x, W, src, dst, cnt, edge_src, y);

    // 3) aggregate v3b: wave per node, shfl-combine, pipelined seg loads
    agg_kernel<<<N_NODES / 4, 256, 0, stream>>>(
        (const uint4*)y, edge_src, cnt, b, (float4*)out);
}

// Round 3
// 114.076 us; speedup vs baseline: 1.0600x; 1.0022x over previous
//
#include <hip/hip_runtime.h>

#define N_NODES 10000
#define N_EDGES 640000
#define D 128
#define NSHARD 8
#define SLOTS 64                       // 64 ushorts = 128 B = ONE cache line per
                                       // (node,shard): no cross-XCD false sharing
#define NODE_STRIDE (NSHARD * SLOTS)   // 512 ushorts = 1 KB per node

typedef __attribute__((ext_vector_type(8))) short bf16x8;
typedef __attribute__((ext_vector_type(4))) float f32x4;

// ws layout (int units):
//   edge_src : 10000*512 ushort = 2,560,000 ints (10.24 MB)
//   cnt      : 8 x 10000        =    80,000 ints (per-shard arrays)
//   y        : 1.28M bf16       =   640,000 ints (y = x @ W^T, bf16)
#define WS_EDGESRC 0
#define WS_CNT     2560000
#define WS_Y       2640000

#define GEMM_BLOCKS 314                // 157 node-tiles x 2 column-halves
#define SCAT_BLOCKS (N_EDGES / 256)    // 2500

__device__ __forceinline__ unsigned bf16_rtne(unsigned u) {
    return (u + 0x7fffu + ((u >> 16) & 1u)) >> 16;
}
__device__ __forceinline__ float blo(unsigned v) { return __uint_as_float(v << 16); }
__device__ __forceinline__ float bhi(unsigned v) { return __uint_as_float(v & 0xffff0000u); }

// ---------------------------------------------------------------------------
// Mega-kernel. KEY CHANGE vs R2: the static LDS tile is HALVED (17.4 KB) by
// splitting each GEMM tile into two column-halves. LDS is allocated for every
// block of a launch -- at 34.8 KB the 2500 scatter blocks (which never touch
// it) were capped at 4 blocks/CU = 16 waves/CU. At 17.4 KB we get 8 blocks/CU
// = 32 waves/CU for the latency-bound scatter phase. GEMM work total is
// unchanged (314 half-blocks instead of 157 full blocks).
// Scatter path is byte-identical to the verified R2 kernel.
// ---------------------------------------------------------------------------
#define WLD 136
__global__ __launch_bounds__(256) void fused_gemm_scatter_kernel(
    const float* __restrict__ x,
    const float* __restrict__ W,
    const int* __restrict__ src,
    const int* __restrict__ dst,
    int* __restrict__ cnt,             // [8][N_NODES], pre-zeroed
    unsigned short* __restrict__ edge_src,
    unsigned short* __restrict__ y) {
    __shared__ __align__(16) unsigned short Wl[64 * WLD];   // 17.4 KB

    int t = threadIdx.x;

    if (blockIdx.x >= GEMM_BLOCKS) {
        int bb = blockIdx.x - GEMM_BLOCKS;
        int i = bb * 256 + t;
        int s = src[i];
        int d = dst[i];
        int sh = bb & (NSHARD - 1);
        int p = atomicAdd(&cnt[sh * N_NODES + d], 1);
        if (p < SLOTS)
            edge_src[d * NODE_STRIDE + sh * SLOTS + p] = (unsigned short)s;
        return;
    }

    int h  = blockIdx.x & 1;           // column half: out cols [h*64, h*64+64)
    int mt = blockIdx.x >> 1;          // node tile (64 nodes)

    {
        // stage W rows [h*64, h*64+64) as bf16: 64 rows x 64 uint2 = 4096
        const uint2* W2 = (const uint2*)W;
        #pragma unroll
        for (int u = t; u < 4096; u += 256) {
            uint2 w = W2[(h * 64 + (u >> 6)) * 64 + (u & 63)];
            unsigned pk = bf16_rtne(w.x) | (bf16_rtne(w.y) << 16);
            *(unsigned*)&Wl[(u >> 6) * WLD + (u & 63) * 2] = pk;
        }
    }
    __syncthreads();

    int wave = t >> 6;
    int lane = t & 63;
    int l16  = lane & 15;
    int quad = lane >> 4;

    int m0 = mt * 64 + wave * 16;
    int anode = m0 + l16;
    if (anode >= N_NODES) anode = N_NODES - 1;

    f32x4 acc[4];
    #pragma unroll
    for (int i = 0; i < 4; ++i) acc[i] = (f32x4){0.f, 0.f, 0.f, 0.f};

    #pragma unroll
    for (int ks = 0; ks < 4; ++ks) {
        const uint4* ap = (const uint4*)(x + anode * D + ks * 32 + quad * 8);
        uint4 a0 = ap[0];
        uint4 a1 = ap[1];
        union { unsigned u[4]; bf16x8 v; } af;
        af.u[0] = bf16_rtne(a0.x) | (bf16_rtne(a0.y) << 16);
        af.u[1] = bf16_rtne(a0.z) | (bf16_rtne(a0.w) << 16);
        af.u[2] = bf16_rtne(a1.x) | (bf16_rtne(a1.y) << 16);
        af.u[3] = bf16_rtne(a1.z) | (bf16_rtne(a1.w) << 16);
        #pragma unroll
        for (int ot = 0; ot < 4; ++ot) {
            bf16x8 bf = *(const bf16x8*)&Wl[(ot * 16 + l16) * WLD + ks * 32 + quad * 8];
            acc[ot] = __builtin_amdgcn_mfma_f32_16x16x32_bf16(af.v, bf, acc[ot], 0, 0, 0);
        }
    }

    #pragma unroll
    for (int ot = 0; ot < 4; ++ot) {
        int o = h * 64 + ot * 16 + l16;
        #pragma unroll
        for (int r = 0; r < 4; ++r) {
            int node = m0 + quad * 4 + r;
            if (node < N_NODES)
                y[node * D + o] = (unsigned short)bf16_rtne(__float_as_uint(acc[ot][r]));
        }
    }
}

// ---------------------------------------------------------------------------
// Aggregation v3b (unchanged from R2): one WAVE per node, quarter-wave `p`
// handles shard-pair {p, p+4}; pipelined seg loads; __shfl_xor combine.
// ---------------------------------------------------------------------------
__global__ __launch_bounds__(256) void agg_kernel(
    const uint4* __restrict__ y4,                // [N_NODES][16] uint4
    const unsigned short* __restrict__ edge_src, // [N_NODES][8][64]
    const int* __restrict__ cnt,                 // [8][N_NODES]
    const float* __restrict__ b,
    float4* __restrict__ out4) {                 // [N_NODES][32] float4
    int t = threadIdx.x;
    int wave = t >> 6;
    int lane = t & 63;
    int p = lane >> 4;               // shard-pair 0..3 (quarter-wave)
    int l = lane & 15;               // col group (8 bf16 = 32 B fp32 out)
    int n = blockIdx.x * 4 + wave;   // 2500 blocks x 4 nodes = 10000 exactly

    int cA = cnt[p * N_NODES + n];
    int cB = cnt[(p + 4) * N_NODES + n];
    if (cA > SLOTS) cA = SLOTS;
    if (cB > SLOTS) cB = SLOTS;
    const unsigned short* segA = edge_src + n * NODE_STRIDE + p * SLOTS;
    const unsigned short* segB = segA + 4 * SLOTS;
    int nb = cA > cB ? cA : cB;

    float acc[8];
    #pragma unroll
    for (int i = 0; i < 8; ++i) acc[i] = 0.f;

    // Unconditional preload of batch 0 (lines are inside the always-
    // allocated edge_src region even when cnt==0).
    uint4 sA = *(const uint4*)segA;
    uint4 sB = *(const uint4*)segB;

    for (int j = 0; j < nb; j += 8) {
        uint4 aV = sA;
        uint4 bV = sB;
        if (j + 8 < nb) {                        // prefetch next batch
            sA = *(const uint4*)(segA + j + 8);
            sB = *(const uint4*)(segB + j + 8);
        }
        unsigned iA[8], iB[8];
        iA[0] = aV.x & 0xffffu; iA[1] = aV.x >> 16;
        iA[2] = aV.y & 0xffffu; iA[3] = aV.y >> 16;
        iA[4] = aV.z & 0xffffu; iA[5] = aV.z >> 16;
        iA[6] = aV.w & 0xffffu; iA[7] = aV.w >> 16;
        iB[0] = bV.x & 0xffffu; iB[1] = bV.x >> 16;
        iB[2] = bV.y & 0xffffu; iB[3] = bV.y >> 16;
        iB[4] = bV.z & 0xffffu; iB[5] = bV.z >> 16;
        iB[6] = bV.w & 0xffffu; iB[7] = bV.w >> 16;
        #pragma unroll
        for (int u = 0; u < 8; ++u) {
            unsigned mA = (j + u < cA) ? 0xffffffffu : 0u;
            unsigned mB = (j + u < cB) ? 0xffffffffu : 0u;
            uint4 vA = y4[iA[u] * 16 + l];       // poison idx stays inside ws
            uint4 vB = y4[iB[u] * 16 + l];
            vA.x &= mA; vA.y &= mA; vA.z &= mA; vA.w &= mA;
            vB.x &= mB; vB.y &= mB; vB.z &= mB; vB.w &= mB;
            acc[0] += blo(vA.x) + blo(vB.x); acc[1] += bhi(vA.x) + bhi(vB.x);
            acc[2] += blo(vA.y) + blo(vB.y); acc[3] += bhi(vA.y) + bhi(vB.y);
            acc[4] += blo(vA.z) + blo(vB.z); acc[5] += bhi(vA.z) + bhi(vB.z);
            acc[6] += blo(vA.w) + blo(vB.w); acc[7] += bhi(vA.w) + bhi(vB.w);
        }
    }

    // Combine the 4 shard-pair partials living in this wave's 4 quarter-
    // waves: butterfly over lane^16 then lane^32.
    #pragma unroll
    for (int k = 0; k < 8; ++k) {
        acc[k] += __shfl_xor(acc[k], 16);
        acc[k] += __shfl_xor(acc[k], 32);
    }

    if (p == 0) {
        const float4* b4 = (const float4*)b;
        float4 b0 = b4[l * 2], b1 = b4[l * 2 + 1];
        out4[n * 32 + l * 2]     = make_float4(acc[0] + b0.x, acc[1] + b0.y,
                                               acc[2] + b0.z, acc[3] + b0.w);
        out4[n * 32 + l * 2 + 1] = make_float4(acc[4] + b1.x, acc[5] + b1.y,
                                               acc[6] + b1.z, acc[7] + b1.w);
    }
}

// ---------------------------------------------------------------------------
extern "C" void kernel_launch(void* const* d_in, const int* in_sizes, int n_in,
                              void* d_out, int out_size, void* d_ws, size_t ws_size,
                              hipStream_t stream) {
    const float* x   = (const float*)d_in[0];
    const int*   src = (const int*)  d_in[1];
    const int*   dst = (const int*)  d_in[2];
    const float* W   = (const float*)d_in[3];
    const float* b   = (const float*)d_in[4];
    float* out = (float*)d_out;

    int* wsI = (int*)d_ws;
    unsigned short* edge_src = (unsigned short*)(wsI + WS_EDGESRC);
    int* cnt = wsI + WS_CNT;
    unsigned short* y = (unsigned short*)(wsI + WS_Y);

    // 1) zero scatter counters (320 KB, per-shard arrays)
    hipMemsetAsync(cnt, 0, NSHARD * N_NODES * sizeof(int), stream);

    // 2) fused: y = x @ W^T (blocks 0..313, half-tiles) + scatter (314..2813)
    fused_gemm_scatter_kernel<<<GEMM_BLOCKS + SCAT_BLOCKS, 256, 0, stream>>>(
        x, W, src, dst, cnt, edge_src, y);

    // 3) aggregate v3b: wave per node, shfl-combine, pipelined seg loads
    agg_kernel<<<N_NODES / 4, 256, 0, stream>>>(
        (const uint4*)y, edge_src, cnt, b, (float4*)out);
}